// Round 8
// baseline (366.896 us; speedup 1.0000x reference)
//
#include <hip/hip_runtime.h>

// Problem constants: B=32 graphs, N=1024 nodes/graph, F=64, D=128, DEG=8
#define E_TOTAL 262144
#define NGRAPH  32
#define EPG     8192
#define EPS_BN  1e-5f
#define NBLK    512
#define NTHR    1024
#define GPX     4     // graphs per XCD
#define BPX     64    // blocks per XCD (NBLK/8)

__device__ __forceinline__ float lrelu(float x){ return x > 0.f ? x : 0.2f * x; }

// LDS union across phases; max member 49664 B -> 2 blocks/CU (99.3 KB of 160 KB).
struct SM {
  union {
    struct { float Ws[64 * 128]; float As_t[64 * 66]; } g;     // 49664 B (gemm)
    struct { int cnt[1024]; int pos[1024]; int wsum[16]; } c;  // 8.3 KB (csr)
    struct { float4 bnred[16 * 64]; float esed[8192]; } b;     // 49152 B (gat)
  };
};

__device__ __forceinline__ unsigned ld_rlx(unsigned* p){
  return __hip_atomic_load(p, __ATOMIC_RELAXED, __HIP_MEMORY_SCOPE_AGENT);
}
__device__ __forceinline__ void st_rlx(unsigned* p, unsigned v){
  __hip_atomic_store(p, v, __ATOMIC_RELAXED, __HIP_MEMORY_SCOPE_AGENT);
}

// ---- XCD-local barrier: syncs the 64 blocks b == x (mod 8). Correct regardless of
// physical XCD placement (device-scope fences); locality is only a perf heuristic. ----
__device__ __forceinline__ void bar_local(unsigned* flags, unsigned* relL,
                                          unsigned ep, int x, int bx){
  __syncthreads();
  int tid = threadIdx.x;
  if (tid == 0){ __threadfence(); st_rlx(&flags[blockIdx.x * 16], ep); }
  if (bx == 0){
    if (tid < 64)
      while (ld_rlx(&flags[(x + 8 * tid) * 16]) < ep) __builtin_amdgcn_s_sleep(1);
    __syncthreads();
    if (tid == 0) st_rlx(&relL[x * 16], ep);
  }
  if (tid == 0){
    while (ld_rlx(&relL[x * 16]) < ep) __builtin_amdgcn_s_sleep(2);
    __threadfence();
  }
  __syncthreads();
}

// ---- global barrier, hierarchical: per-XCD scan then 8-word scan by block 0 ----
__device__ __forceinline__ void bar_global(unsigned* flags, unsigned* xd, unsigned* rel,
                                           unsigned ep, int x, int bx){
  __syncthreads();
  int tid = threadIdx.x;
  if (tid == 0){ __threadfence(); st_rlx(&flags[blockIdx.x * 16], ep); }
  if (bx == 0){
    if (tid < 64)
      while (ld_rlx(&flags[(x + 8 * tid) * 16]) < ep) __builtin_amdgcn_s_sleep(1);
    __syncthreads();
    if (tid == 0) st_rlx(&xd[x * 16], ep);
    if (x == 0 && tid < 8)
      while (ld_rlx(&xd[tid * 16]) < ep) __builtin_amdgcn_s_sleep(1);
    __syncthreads();
    if (x == 0 && tid == 0) st_rlx(rel, ep);
  }
  if (tid == 0){
    while (ld_rlx(rel) < ep) __builtin_amdgcn_s_sleep(4);
    __threadfence();
  }
  __syncthreads();
}

// ---- GEMM + attention terms, XCD-pinned tiles; 16 waves, 64-row tiles ----
template<int K>
__device__ void dev_gemm(SM& sm, const float* __restrict__ A, const float* __restrict__ W,
                         const float* __restrict__ bnp, float invM,
                         const float* __restrict__ a_s, const float* __restrict__ a_d,
                         float* __restrict__ C, float* __restrict__ es, float* __restrict__ ed,
                         int tpg, int x, int wl, int nw){
  int tid = threadIdx.x, lane = tid & 63, rg = tid >> 6;
  float mu0 = 0.f, rs0 = 1.f, mu1 = 0.f, rs1 = 1.f;
  if (bnp){
    float s0 = 0.f, q0 = 0.f, s1 = 0.f, q1 = 0.f;
    #pragma unroll
    for (int xx = 0; xx < 8; ++xx){
      const float* b = bnp + xx * 256;
      s0 += b[lane];      q0 += b[128 + lane];
      s1 += b[64 + lane]; q1 += b[192 + lane];
    }
    mu0 = s0 * invM; rs0 = rsqrtf(q0 * invM - mu0 * mu0 + EPS_BN);
    mu1 = s1 * invM; rs1 = rsqrtf(q1 * invM - mu1 * mu1 + EPS_BN);
  }
  float2 as2 = ((const float2*)a_s)[lane];
  float2 ad2 = ((const float2*)a_d)[lane];
  int ltiles = GPX * tpg;
  for (int lt = wl; lt < ltiles; lt += nw){
    int g = x + 8 * (lt / tpg);
    int row0 = (g * tpg + (lt % tpg)) << 6;
    float2 acc[4] = {};
    for (int k0 = 0; k0 < K; k0 += 64){
      float mu = k0 ? mu1 : mu0, rs = k0 ? rs1 : rs0;
      __syncthreads();
      for (int i = tid; i < 8192; i += NTHR)
        sm.g.Ws[i] = W[(size_t)(k0 + (i >> 7)) * 128 + (i & 127)];
      #pragma unroll
      for (int it = 0; it < 4; ++it){
        int r = it * 16 + rg;
        float v = A[(size_t)(row0 + r) * K + k0 + lane];
        sm.g.As_t[lane * 66 + r] = (v - mu) * rs;
      }
      __syncthreads();
      #pragma unroll 8
      for (int kk = 0; kk < 64; ++kk){
        float2 w   = *(float2*)&sm.g.Ws[kk * 128 + lane * 2];
        float2 a01 = *(float2*)&sm.g.As_t[kk * 66 + rg * 4];
        float2 a23 = *(float2*)&sm.g.As_t[kk * 66 + rg * 4 + 2];
        acc[0].x = fmaf(a01.x, w.x, acc[0].x); acc[0].y = fmaf(a01.x, w.y, acc[0].y);
        acc[1].x = fmaf(a01.y, w.x, acc[1].x); acc[1].y = fmaf(a01.y, w.y, acc[1].y);
        acc[2].x = fmaf(a23.x, w.x, acc[2].x); acc[2].y = fmaf(a23.x, w.y, acc[2].y);
        acc[3].x = fmaf(a23.y, w.x, acc[3].x); acc[3].y = fmaf(a23.y, w.y, acc[3].y);
      }
    }
    #pragma unroll
    for (int i = 0; i < 4; ++i){
      int r = row0 + rg * 4 + i;
      ((float2*)C)[(size_t)r * 64 + lane] = acc[i];
      float e1 = acc[i].x * as2.x + acc[i].y * as2.y;
      float e2 = acc[i].x * ad2.x + acc[i].y * ad2.y;
      #pragma unroll
      for (int o = 32; o; o >>= 1){ e1 += __shfl_xor(e1, o); e2 += __shfl_xor(e2, o); }
      if (lane == 0){ es[r] = e1; ed[r] = e2; }
    }
  }
}

// ---- per-graph counting sort by dst + inline dedupe-for-next-layer; one block/graph ----
__device__ void dev_csr(SM& sm, const int* __restrict__ src0, const int* __restrict__ dst0,
                        const unsigned char* __restrict__ maskIn,
                        int* __restrict__ csr_src, int* __restrict__ row_start,
                        int* __restrict__ row_cnt, int shift, int Npg,
                        unsigned char* __restrict__ maskOut, unsigned int* __restrict__ bitmap,
                        int shiftN, int log2NpgN, int g){
  int t = threadIdx.x;
  int ebase = g * EPG;
  unsigned int* bmg = nullptr;
  if (bitmap){
    int words = 1 << (2 * log2NpgN - 5);
    bmg = bitmap + (size_t)g * words;
    for (int i = t; i < words; i += NTHR) bmg[i] = 0;
  }
  if (t < Npg) sm.c.cnt[t] = 0;
  __syncthreads();
  unsigned keep = 0;
  #pragma unroll
  for (int k = 0; k < 8; ++k){
    int e = ebase + t + k * NTHR;
    int sv = src0[e], dv = dst0[e];
    bool act = maskIn ? (maskIn[e] != 0) : (sv != dv);
    if (act){
      keep |= (1u << k);
      atomicAdd(&sm.c.cnt[(dv >> shift) & (Npg - 1)], 1);
    }
    if (maskOut){
      unsigned char m2 = 0;
      if (act){
        int s2 = sv >> shiftN, d2 = dv >> shiftN;
        if (s2 != d2){
          int NpgN = 1 << log2NpgN;
          unsigned key = ((unsigned)(s2 & (NpgN - 1)) << log2NpgN) | (unsigned)(d2 & (NpgN - 1));
          unsigned bit = 1u << (key & 31u);
          unsigned old = atomicOr(&bmg[key >> 5], bit);
          m2 = (old & bit) ? 0 : 1;
        }
      }
      maskOut[e] = m2;
    }
  }
  __syncthreads();
  int c = (t < Npg) ? sm.c.cnt[t] : 0;
  int lane = t & 63, w = t >> 6;
  int v = c;
  #pragma unroll
  for (int o = 1; o < 64; o <<= 1){
    int u = __shfl_up(v, o);
    if (lane >= o) v += u;
  }
  if (lane == 63) sm.c.wsum[w] = v;
  __syncthreads();
  if (t == 0){
    int run = 0;
    #pragma unroll
    for (int i = 0; i < 16; ++i){ int x2 = sm.c.wsum[i]; sm.c.wsum[i] = run; run += x2; }
  }
  __syncthreads();
  int excl = v - c + sm.c.wsum[w];
  if (t < Npg){
    sm.c.pos[t] = excl;
    row_start[g * Npg + t] = ebase + excl;
    row_cnt[g * Npg + t]   = c;
  }
  __syncthreads();
  #pragma unroll
  for (int k = 0; k < 8; ++k){
    if (keep & (1u << k)){
      int e = ebase + t + k * NTHR;
      int d = (dst0[e] >> shift) & (Npg - 1);
      int p = atomicAdd(&sm.c.pos[d], 1);
      csr_src[ebase + p] = src0[e] >> shift;
    }
  }
}

// ---- one GAT node; es/ed from LDS. Fast path (cnt<=64): single gather, exp reused ----
__device__ float2 dev_gat_node(const float2* __restrict__ h2, const float* __restrict__ esl,
                               const float* __restrict__ edl, const int* __restrict__ csr_src,
                               const int* __restrict__ rs_, const int* __restrict__ rc_,
                               float2 bv, int n, int nmask, int lane){
  int start = rs_[n];
  int cnt   = rc_[n];
  int nl = n & nmask;
  float edn = edl[nl];
  float selfl = lrelu(esl[nl] + edn);
  float2 hv = h2[(size_t)n * 64 + lane];
  float2 acc;
  float den;
  if (__builtin_expect(cnt <= 64, 1)){
    int s = 0; float l = -1e30f;
    bool act = lane < cnt;
    if (act){ s = csr_src[start + lane]; l = lrelu(esl[s & nmask] + edn); }
    float m = fmaxf(l, selfl);
    #pragma unroll
    for (int o = 32; o; o >>= 1) m = fmaxf(m, __shfl_xor(m, o));
    float w = act ? __expf(l - m) : 0.f;
    float sw = __expf(selfl - m);
    float d = w;
    #pragma unroll
    for (int o = 32; o; o >>= 1) d += __shfl_xor(d, o);
    den = d + sw;
    acc.x = sw * hv.x; acc.y = sw * hv.y;
    int k = 0;
    for (; k + 8 <= cnt; k += 8){
      int ss[8]; float ww[8]; float2 hh[8];
      #pragma unroll
      for (int i = 0; i < 8; ++i){ ss[i] = __shfl(s, k + i); ww[i] = __shfl(w, k + i); }
      #pragma unroll
      for (int i = 0; i < 8; ++i) hh[i] = h2[(size_t)ss[i] * 64 + lane];
      #pragma unroll
      for (int i = 0; i < 8; ++i){
        acc.x = fmaf(ww[i], hh[i].x, acc.x);
        acc.y = fmaf(ww[i], hh[i].y, acc.y);
      }
    }
    for (; k < cnt; ++k){
      int s2 = __shfl(s, k); float w2 = __shfl(w, k);
      float2 hh = h2[(size_t)s2 * 64 + lane];
      acc.x = fmaf(w2, hh.x, acc.x);
      acc.y = fmaf(w2, hh.y, acc.y);
    }
  } else {
    // slow path: two-pass online softmax (rare)
    float m_l = -1e30f, d_l = 0.f;
    for (int c0 = 0; c0 < cnt; c0 += 64){
      int j = c0 + lane;
      if (j < cnt){
        int s = csr_src[start + j];
        float l = lrelu(esl[s & nmask] + edn);
        float mn = fmaxf(m_l, l);
        d_l = d_l * __expf(m_l - mn) + __expf(l - mn);
        m_l = mn;
      }
    }
    #pragma unroll
    for (int o = 32; o; o >>= 1){
      float m2 = __shfl_xor(m_l, o), d2 = __shfl_xor(d_l, o);
      float mn = fmaxf(m_l, m2);
      d_l = d_l * __expf(m_l - mn) + d2 * __expf(m2 - mn);
      m_l = mn;
    }
    float mf = fmaxf(m_l, selfl);
    den = d_l * __expf(m_l - mf) + __expf(selfl - mf);
    float sw = __expf(selfl - mf);
    acc.x = sw * hv.x; acc.y = sw * hv.y;
    for (int c0 = 0; c0 < cnt; c0 += 64){
      int j = c0 + lane;
      int s_j = 0; float w_j = 0.f;
      if (j < cnt){
        s_j = csr_src[start + j];
        w_j = __expf(lrelu(esl[s_j & nmask] + edn) - mf);
      }
      int rem = min(64, cnt - c0);
      for (int k = 0; k < rem; ++k){
        int s2 = __shfl(s_j, k); float w2 = __shfl(w_j, k);
        float2 hh = h2[(size_t)s2 * 64 + lane];
        acc.x = fmaf(w2, hh.x, acc.x);
        acc.y = fmaf(w2, hh.y, acc.y);
      }
    }
  }
  float inv = 1.f / den;
  return make_float2(fmaxf(acc.x * inv + bv.x, 0.f), fmaxf(acc.y * inv + bv.y, 0.f));
}

// ---- GAT + pool + BN partial, XCD-pinned; es/ed staged in LDS for the 4 graphs ----
__device__ void dev_gat(SM& sm, const float* __restrict__ h, const float* __restrict__ es,
                        const float* __restrict__ ed, const int* __restrict__ csr_src,
                        const int* __restrict__ rs, const int* __restrict__ rc,
                        const float* __restrict__ bias, float* __restrict__ xout,
                        float* __restrict__ bnp_x, int ppg, int lppg,
                        int x, int wl, int nw){
  int tid = threadIdx.x, lane = tid & 63, wave = tid >> 6;
  int Npg = 2 * ppg, nmask = Npg - 1;
  // stage es/ed for this XCD's 4 graphs into LDS
  for (int gi = 0; gi < GPX; ++gi){
    int g = x + 8 * gi;
    for (int i = tid; i < Npg; i += NTHR){
      sm.b.esed[gi * Npg + i]            = es[g * Npg + i];
      sm.b.esed[4 * Npg + gi * Npg + i]  = ed[g * Npg + i];
    }
  }
  __syncthreads();
  const float2* h2 = (const float2*)h;
  float2 bv = ((const float2*)bias)[lane];
  float4 part = make_float4(0.f, 0.f, 0.f, 0.f);
  int lpairs = GPX * ppg;
  for (int lp = wl * 16 + wave; lp < lpairs; lp += nw * 16){
    int gi = lp >> lppg;
    int pp = lp & (ppg - 1);
    int g = x + 8 * gi;
    int p = g * ppg + pp;
    const float* esl = &sm.b.esed[gi * Npg];
    const float* edl = &sm.b.esed[4 * Npg + gi * Npg];
    float2 o0 = dev_gat_node(h2, esl, edl, csr_src, rs, rc, bv, 2 * p,     nmask, lane);
    float2 o1 = dev_gat_node(h2, esl, edl, csr_src, rs, rc, bv, 2 * p + 1, nmask, lane);
    float2 pl; pl.x = fmaxf(o0.x, o1.x); pl.y = fmaxf(o0.y, o1.y);
    ((float2*)xout)[(size_t)p * 64 + lane] = pl;
    part.x += pl.x; part.y += pl.y; part.z += pl.x * pl.x; part.w += pl.y * pl.y;
  }
  __syncthreads();
  sm.b.bnred[wave * 64 + lane] = part;
  __syncthreads();
  if (wave == 0){
    float4 a = sm.b.bnred[lane];
    #pragma unroll
    for (int w = 1; w < 16; ++w){
      float4 b = sm.b.bnred[w * 64 + lane];
      a.x += b.x; a.y += b.y; a.z += b.z; a.w += b.w;
    }
    atomicAdd(&bnp_x[2 * lane],           a.x);
    atomicAdd(&bnp_x[2 * lane + 1],       a.y);
    atomicAdd(&bnp_x[128 + 2 * lane],     a.z);
    atomicAdd(&bnp_x[128 + 2 * lane + 1], a.w);
  }
}

// ---- persistent mega-kernel: 3 local + 3 global barriers, 2 blocks/CU ----
__global__ __launch_bounds__(NTHR, 8)
void mega(const float* __restrict__ x0, const float* __restrict__ W0,
          const float* __restrict__ W1, const float* __restrict__ W2,
          const float* __restrict__ attS, const float* __restrict__ attD,
          const float* __restrict__ bias,
          const int* __restrict__ src0, const int* __restrict__ dst0,
          float* Hbuf, float* Xbuf, float* es, float* ed,
          int* csr1, int* rs1, int* rc1,
          int* csr2, int* rs2, int* rc2,
          int* csr3, int* rs3, int* rc3,
          unsigned char* mask2, unsigned char* mask3,
          unsigned int* bitmap0, unsigned int* bitmap1,
          float* bnp, unsigned* flags, unsigned* relL, unsigned* xd, unsigned* rel,
          float* out){
  __shared__ SM sm;
  int blk = blockIdx.x;
  int x  = blk & 7;      // XCD heuristic (round-robin dispatch)
  int bx = blk >> 3;     // block index within XCD (0..63)
  int tid = threadIdx.x;
  // bnp layout: [layer][xcd][256] (128 sums + 128 sumsqs)

  // P1: csr L1 (bx 0..3, graph x+8*bx) || gemm L1 (bx 4..63); bx==4 zeroes bnp slices
  if (bx < GPX){
    dev_csr(sm, src0, dst0, nullptr, csr1, rs1, rc1, 0, 1024, mask2, bitmap0, 1, 9,
            x + 8 * bx);
  } else {
    if (bx == 4){
      for (int i = tid; i < 768; i += NTHR){
        int l = i >> 8, c = i & 255;
        bnp[(l * 8 + x) * 256 + c] = 0.f;
      }
    }
    dev_gemm<64>(sm, x0, W0, nullptr, 0.f, attS, attD, Hbuf, es, ed, 16, x, bx - 4, 60);
  }
  bar_local(flags, relL, 1, x, bx);

  // P2: csr L2 (bx 0..3) || gat L1 + pool + bn0 (bx 4..63)
  if (bx < GPX){
    dev_csr(sm, src0, dst0, mask2, csr2, rs2, rc2, 1, 512, mask3, bitmap1, 2, 8,
            x + 8 * bx);
  } else {
    dev_gat(sm, Hbuf, es, ed, csr1, rs1, rc1, bias, Xbuf, bnp + x * 256,
            512, 9, x, bx - 4, 60);
  }
  bar_global(flags, xd, rel, 2, x, bx);   // bn0 must be global

  // P3: csr L3 (bx 0..3) || gemm L2 (bx 4..63)
  if (bx < GPX){
    dev_csr(sm, src0, dst0, mask3, csr3, rs3, rc3, 2, 256, nullptr, nullptr, 0, 0,
            x + 8 * bx);
  } else {
    dev_gemm<128>(sm, Xbuf, W1, bnp, 1.f / 16384.f, attS + 128, attD + 128,
                  Hbuf, es, ed, 8, x, bx - 4, 60);
  }
  bar_local(flags, relL, 3, x, bx);

  // P4: gat L2 + pool + bn1 (all)
  dev_gat(sm, Hbuf, es, ed, csr2, rs2, rc2, bias + 128, Xbuf, bnp + (8 + x) * 256,
          256, 8, x, bx, 64);
  bar_global(flags, xd, rel, 4, x, bx);   // bn1 global

  // P5: gemm L3 (16 tiles/XCD over 64 blocks)
  dev_gemm<128>(sm, Xbuf, W2, bnp + 2048, 1.f / 8192.f, attS + 256, attD + 256,
                Hbuf, es, ed, 4, x, bx, 64);
  bar_local(flags, relL, 5, x, bx);

  // P6: gat L3 + pool + bn2 (all)
  dev_gat(sm, Hbuf, es, ed, csr3, rs3, rc3, bias + 256, Xbuf, bnp + (16 + x) * 256,
          128, 7, x, bx, 64);
  bar_global(flags, xd, rel, 6, x, bx);   // bn2 global

  // P7: final BatchNorm apply -> out, XCD-pinned rows (1 float2/thread, bx 0..31)
  {
    const float* b2 = bnp + 2 * 2048;
    int lt = bx * NTHR + tid;             // 0..65535 within XCD; first 32768 work
    if (lt < 32768){
      int row_l = lt >> 6;                // 0..511
      int g = x + 8 * (row_l >> 7);
      int row = g * 128 + (row_l & 127);
      int c2 = lt & 63;
      float s0 = 0.f, q0 = 0.f, s1 = 0.f, q1 = 0.f;
      #pragma unroll
      for (int xx = 0; xx < 8; ++xx){
        const float* b = b2 + xx * 256;
        s0 += b[2 * c2];     q0 += b[128 + 2 * c2];
        s1 += b[2 * c2 + 1]; q1 += b[128 + 2 * c2 + 1];
      }
      float mu0 = s0 * (1.f / 4096.f), mu1 = s1 * (1.f / 4096.f);
      float r0 = rsqrtf(q0 * (1.f / 4096.f) - mu0 * mu0 + EPS_BN);
      float r1 = rsqrtf(q1 * (1.f / 4096.f) - mu1 * mu1 + EPS_BN);
      float2 v = ((const float2*)Xbuf)[(size_t)row * 64 + c2];
      ((float2*)out)[(size_t)row * 64 + c2] =
          make_float2((v.x - mu0) * r0, (v.y - mu1) * r1);
    }
  }
}

extern "C" void kernel_launch(void* const* d_in, const int* in_sizes, int n_in,
                              void* d_out, int out_size, void* d_ws, size_t ws_size,
                              hipStream_t stream){
  const float* x0   = (const float*)d_in[0];
  const float* W0   = (const float*)d_in[1];
  const float* W1   = (const float*)d_in[2];
  const float* W2   = (const float*)d_in[3];
  const float* attS = (const float*)d_in[4];
  const float* attD = (const float*)d_in[5];
  const float* bias = (const float*)d_in[6];
  const int*   src0 = (const int*)d_in[7];
  const int*   dst0 = src0 + E_TOTAL;
  float* out = (float*)d_out;

  char* ws = (char*)d_ws;
  float*         Hbuf    = (float*)(ws);                          // 16 MB
  float*         Xbuf    = (float*)(ws + (16u << 20));            //  8 MB
  float*         es      = (float*)(ws + (24u << 20));            // 128 KB
  float*         ed      = (float*)(ws + (24u << 20) + (128u << 10));
  int*           csr1    = (int*)  (ws + (25u << 20));            // 1 MB
  int*           csr2    = (int*)  (ws + (26u << 20));            // 1 MB
  int*           csr3    = (int*)  (ws + (27u << 20));            // 1 MB
  int*           rs1     = (int*)  (ws + (28u << 20));            // 128 KB each
  int*           rc1     = (int*)  (ws + (28u << 20) + 1 * (128u << 10));
  int*           rs2     = (int*)  (ws + (28u << 20) + 2 * (128u << 10));
  int*           rc2     = (int*)  (ws + (28u << 20) + 3 * (128u << 10));
  int*           rs3     = (int*)  (ws + (28u << 20) + 4 * (128u << 10));
  int*           rc3     = (int*)  (ws + (28u << 20) + 5 * (128u << 10));
  unsigned char* mask2   = (unsigned char*)(ws + (29u << 20));           // 256 KB
  unsigned char* mask3   = (unsigned char*)(ws + (29u << 20) + (256u << 10));
  unsigned int*  bitmap0 = (unsigned int*)(ws + (30u << 20));            // 1 MB
  unsigned int*  bitmap1 = (unsigned int*)(ws + (31u << 20));            // 256 KB
  unsigned*      flags   = (unsigned*)(ws + (31u << 20) + (256u << 10)); // 512*64 B
  unsigned*      relL    = flags + 512 * 16;                              // 8*64 B
  unsigned*      xd      = relL  + 8 * 16;                                // 8*64 B
  unsigned*      rel     = xd    + 8 * 16;                                // 64 B
  float*         bnp     = (float*)(ws + (31u << 20) + (306u << 10));     // 3*8*256 f

  // zero flags + relL + xd + rel (33856 B, contiguous); bnp zeroed in-kernel
  hipMemsetAsync(flags, 0, (512 * 16 + 8 * 16 + 8 * 16 + 16) * sizeof(unsigned), stream);
  hipLaunchKernelGGL(mega, dim3(NBLK), dim3(NTHR), 0, stream,
                     x0, W0, W1, W2, attS, attD, bias, src0, dst0,
                     Hbuf, Xbuf, es, ed,
                     csr1, rs1, rc1, csr2, rs2, rc2, csr3, rs3, rc3,
                     mask2, mask3, bitmap0, bitmap1, bnp, flags, relL, xd, rel, out);
}